// Round 9
// baseline (363.260 us; speedup 1.0000x reference)
//
#include <hip/hip_runtime.h>
#include <hip/hip_bf16.h>

#define N_INS 16384
#define N_ATT 8192
#define KDIM  64

typedef __attribute__((ext_vector_type(8))) short bf16x8;
typedef __attribute__((ext_vector_type(4))) float f32x4;

// ws layout (bytes) — every buffer fully overwritten each launch (no zero-init;
// tickets zeroed by K1):
// 0:       bf16 Ucb[8192*64] (1 MiB, fragment-order tiles)
// 1048576: float segparts[96][4096] ([0,64)=Ur, [64,96)=Uc)
// 2621440: float Gpart[2048]
// 2629632: float cpr[64][64]
// 2646016: float cpc[32][64]
// 2654208: double Uupart[96]
// 2654976: float Aseg[4096]
// 2671360: float Bseg[4096]
// 2687744: float TrrG[4096]
// 2704128: unsigned tickets[2]
#define OFF_UCB    0
#define OFF_SEGP   1048576
#define OFF_GPART  2621440
#define OFF_CPR    2629632
#define OFF_CPC    2646016
#define OFF_UUP    2654208
#define OFF_ASEG   2654976
#define OFF_BSEG   2671360
#define OFF_TRR    2687744
#define OFF_TK     2704128

#define NBLK_HEAVY 2048
#define NBLK_PASS  96
#define NBLK_K2    (NBLK_HEAVY + NBLK_PASS)

__device__ __forceinline__ unsigned short f2bf(float x) {
    unsigned u = __float_as_uint(x);
    u = (u + 0x7FFFu + ((u >> 16) & 1u)) >> 16;   // RNE
    return (unsigned short)u;
}

__device__ __forceinline__ float wave_red(float v) {
#pragma unroll
    for (int o = 32; o > 0; o >>= 1) v += __shfl_down(v, o, 64);
    return v;
}

// ---- K1: convert Uc->bf16 fragment tiles, colsum partials, zero tickets ----
// blocks [0,128): convert. [128,192): Ur colsums (256 rows) -> cpr.
// [192,224): Uc colsums (256 rows) -> cpc.
__global__ void k_prep(const float* __restrict__ Ur, const float* __restrict__ Uc,
                       float* __restrict__ cpr, float* __restrict__ cpc,
                       unsigned short* __restrict__ Ucb, unsigned* __restrict__ tickets) {
    int blk = blockIdx.x, tid = threadIdx.x;
    if (blk < 128) {
        int gid = blk * 256 + tid;
        for (int c = gid; c < N_ATT * 8; c += 32768) {
            int r = c >> 3, q = c & 7;
            const float4* src = (const float4*)(Uc + (size_t)r * 64 + q * 8);
            float4 x0 = src[0], x1 = src[1];
            uint4 v;
            v.x = (unsigned)f2bf(x0.x) | ((unsigned)f2bf(x0.y) << 16);
            v.y = (unsigned)f2bf(x0.z) | ((unsigned)f2bf(x0.w) << 16);
            v.z = (unsigned)f2bf(x1.x) | ((unsigned)f2bf(x1.y) << 16);
            v.w = (unsigned)f2bf(x1.z) | ((unsigned)f2bf(x1.w) << 16);
            int m = r & 15, t = r >> 4;
            int woff = (q < 4) ? (q * 256 + m * 16) : (1024 + (q - 4) * 256 + m * 16);
            *(uint4*)((unsigned char*)Ucb + (size_t)t * 2048 + woff) = v;
        }
        return;
    }
    if (blk == 128 && tid == 0) { tickets[0] = 0u; tickets[1] = 0u; }
    __shared__ float cs2[256];
    bool isUr = blk < 192;
    int b = isUr ? (blk - 128) : (blk - 192);
    const float* base = (isUr ? Ur : Uc) + (size_t)b * 256 * KDIM;
    float* dst = (isUr ? cpr : cpc) + b * 64;
    int col = tid & 63, r0 = tid >> 6;
    float s = 0.f;
    for (int r = r0; r < 256; r += 4) s += base[r * KDIM + col];
    cs2[tid] = s;
    __syncthreads();
    if (tid < 64) dst[tid] = cs2[tid] + cs2[tid + 64] + cs2[tid + 128] + cs2[tid + 192];
}

// ---- K2: heavy G (blocks<2048) + pass (96) + ticketed red + ticketed final ----
// 4 dispatches -> 2: the ~30-57us per-dispatch boundary cost (k_pass measured
// 57us at 0.5% VALUBusy across three different implementations) dominates.
// Inter-block deps handled by device-scope ticket counters (threadfence +
// atomicAdd); "last" blocks only consume fenced-published data -> no spin,
// no dispatch-order assumptions, no deadlock.
__global__ __launch_bounds__(256)
void k_main(const float* __restrict__ Ur, const float* __restrict__ Uc,
            const unsigned char* __restrict__ Ucb,
            float* __restrict__ Gpart, float* __restrict__ segparts,
            const float* __restrict__ cpr, const float* __restrict__ cpc,
            double* __restrict__ Uupart,
            float* __restrict__ Aseg, float* __restrict__ Bseg,
            float* __restrict__ TrrG, unsigned* __restrict__ tickets,
            float* __restrict__ out) {
    __shared__ __align__(16) unsigned char smem[17696];
    __shared__ int flag1, flag2;
    int tid = threadIdx.x, blk = blockIdx.x;
    int wvi = tid >> 6, lane = tid & 63;

    if (blk < NBLK_HEAVY) {
        // ---------- heavy: G += d*log2(d), bf16 MFMA, register-pipelined B ----------
        float* gsh = (float*)smem;
        int quad = lane >> 4, m = lane & 15;
        int rb = blk & 127, cc = blk >> 7;
        int row0 = rb * 128 + wvi * 32;
        bf16x8 a[2][2];
#pragma unroll
        for (int t = 0; t < 2; ++t) {
            int ridx = row0 + t * 16 + m;
            const float* rp = Ur + (size_t)ridx * 64 + quad * 8;
#pragma unroll
            for (int h = 0; h < 2; ++h) {
                const float* rph = rp + h * 32;
                float4 x0 = *(const float4*)rph;
                float4 x1 = *(const float4*)(rph + 4);
                bf16x8 f;
                f[0] = (short)f2bf(x0.x); f[1] = (short)f2bf(x0.y);
                f[2] = (short)f2bf(x0.z); f[3] = (short)f2bf(x0.w);
                f[4] = (short)f2bf(x1.x); f[5] = (short)f2bf(x1.y);
                f[6] = (short)f2bf(x1.z); f[7] = (short)f2bf(x1.w);
                a[t][h] = f;
            }
        }
        const unsigned char* gB = Ucb + (size_t)(cc * 32) * 2048 + lane * 16;
        bf16x8 c00 = *(const bf16x8*)(gB);
        bf16x8 c01 = *(const bf16x8*)(gB + 1024);
        bf16x8 c10 = *(const bf16x8*)(gB + 2048);
        bf16x8 c11 = *(const bf16x8*)(gB + 3072);
        float g = 0.f;
#pragma unroll 1
        for (int pt = 0; pt < 16; ++pt) {
            int npt = (pt < 15) ? (pt + 1) : 15;
            const unsigned char* nb = gB + (size_t)npt * 4096;
            bf16x8 n00 = *(const bf16x8*)(nb);
            bf16x8 n01 = *(const bf16x8*)(nb + 1024);
            bf16x8 n10 = *(const bf16x8*)(nb + 2048);
            bf16x8 n11 = *(const bf16x8*)(nb + 3072);
            f32x4 acc00 = {0.f,0.f,0.f,0.f}, acc01 = {0.f,0.f,0.f,0.f};
            f32x4 acc10 = {0.f,0.f,0.f,0.f}, acc11 = {0.f,0.f,0.f,0.f};
            acc00 = __builtin_amdgcn_mfma_f32_16x16x32_bf16(a[0][0], c00, acc00, 0, 0, 0);
            acc00 = __builtin_amdgcn_mfma_f32_16x16x32_bf16(a[0][1], c01, acc00, 0, 0, 0);
            acc10 = __builtin_amdgcn_mfma_f32_16x16x32_bf16(a[1][0], c00, acc10, 0, 0, 0);
            acc10 = __builtin_amdgcn_mfma_f32_16x16x32_bf16(a[1][1], c01, acc10, 0, 0, 0);
            acc01 = __builtin_amdgcn_mfma_f32_16x16x32_bf16(a[0][0], c10, acc01, 0, 0, 0);
            acc01 = __builtin_amdgcn_mfma_f32_16x16x32_bf16(a[0][1], c11, acc01, 0, 0, 0);
            acc11 = __builtin_amdgcn_mfma_f32_16x16x32_bf16(a[1][0], c10, acc11, 0, 0, 0);
            acc11 = __builtin_amdgcn_mfma_f32_16x16x32_bf16(a[1][1], c11, acc11, 0, 0, 0);
            // tile-sum is permutation-invariant -> C/D layout irrelevant;
            // dropping +eps*S (~2e-6 vs d~16) perturbs mi_org ~2e-7 << threshold
#pragma unroll
            for (int e = 0; e < 4; ++e) {
                float d0 = acc00[e]; g += d0 * __log2f(d0);
                float d1 = acc01[e]; g += d1 * __log2f(d1);
                float d2 = acc10[e]; g += d2 * __log2f(d2);
                float d3 = acc11[e]; g += d3 * __log2f(d3);
            }
            c00 = n00; c01 = n01; c10 = n10; c11 = n11;
        }
        float gw = wave_red(g);
        if (lane == 0) gsh[wvi] = gw;
        __syncthreads();
        if (tid == 0) Gpart[blk] = gsh[0] + gsh[1] + gsh[2] + gsh[3];
    } else {
        // ---------- pass: argmax + weighted sums (R8 structure, proven) ----------
        float* Part = (float*)smem;
        float* wv   = (float*)(smem + 16384);
        int*   bins = (int*)(smem + 16640);
        float* psum = (float*)(smem + 17664);
        bool isUr = blk < (NBLK_HEAVY + 64);
        int b = isUr ? (blk - NBLK_HEAVY) : (blk - NBLK_HEAVY - 64);
        const float* M = isUr ? Ur : Uc;
        const float* cpw = isUr ? cpc : cpr;
        int nbw = isUr ? 32 : 64;
        int segidx = isUr ? b : (64 + b);
        int base_row = b * 256;

        if (tid < 64) {
            float s = 0.f;
            for (int p = 0; p < nbw; ++p) s += cpw[p * 64 + tid];
            wv[tid] = s;
        }
        for (int i = tid; i < 4096; i += 256) Part[i] = 0.f;
        __syncthreads();

        {   // phase 1: row-per-thread argmax + dot (pure VALU)
            int row = base_row + tid;
            const float* rp = M + (size_t)row * KDIM;
            float best = -1e30f; int bidx = 0; float u = 0.f;
#pragma unroll
            for (int k = 0; k < 64; k += 4) {
                float4 v = *(const float4*)(rp + k);
                if (v.x > best) { best = v.x; bidx = k; }
                if (v.y > best) { best = v.y; bidx = k + 1; }
                if (v.z > best) { best = v.z; bidx = k + 2; }
                if (v.w > best) { best = v.w; bidx = k + 3; }
                u += v.x * wv[k] + v.y * wv[k + 1] + v.z * wv[k + 2] + v.w * wv[k + 3];
            }
            bins[tid] = bidx;
            float p = u * __log2f(u);
            float pw = wave_red(p);
            if (lane == 0) psum[wvi] = pw;
        }
        __syncthreads();
        {   // phase 2: one fire-and-forget ds_add per row per wave
            int r0 = wvi * 64;
            const float* Mb = M + (size_t)(base_row + r0) * 64 + lane;
#pragma unroll 4
            for (int r = 0; r < 64; ++r) {
                int bb = bins[r0 + r];
                float val = Mb[(size_t)r * 64];
                atomicAdd(&Part[bb * 64 + lane], val);
            }
        }
        __syncthreads();
        float* sp = segparts + (size_t)segidx * 4096;
        for (int i = tid; i < 4096; i += 256) sp[i] = Part[i];
        if (tid == 0)
            Uupart[segidx] = (double)psum[0] + (double)psum[1]
                           + (double)psum[2] + (double)psum[3];
        // pass ticket: last pass-finisher folds segparts -> Aseg/Bseg
        // (overlaps with heavy blocks still running)
        __threadfence();
        __syncthreads();
        if (tid == 0) { unsigned old = atomicAdd(&tickets[0], 1u); flag1 = (old == NBLK_PASS - 1); }
        __syncthreads();
        if (flag1) {
            for (int j = tid; j < 4096; j += 256) {
                float sa = 0.f, sb = 0.f;
                for (int p = 0; p < 64; ++p)  sa += segparts[(size_t)p * 4096 + j];
                for (int p = 64; p < 96; ++p) sb += segparts[(size_t)p * 4096 + j];
                Aseg[j] = sa; Bseg[j] = sb;
            }
        }
    }

    // ---------- final ticket: last block overall assembles the loss ----------
    __threadfence();
    __syncthreads();
    if (tid == 0) { unsigned old = atomicAdd(&tickets[1], 1u); flag2 = (old == NBLK_K2 - 1); }
    __syncthreads();
    if (!flag2) return;
    __threadfence();

    double* red = (double*)smem;             // smem repurposed (post-sync)
    double* Prx = (double*)(smem + 2048);
    double* Pry = (double*)(smem + 2560);
    double* sc  = (double*)(smem + 3072);    // [0]=S [1]=G [2]=Uu [3]=Vv
    if (tid < 64) {
        double sa = 0.0, sb = 0.0;
        for (int p = 0; p < 64; ++p) sa += (double)cpr[p * 64 + tid];
        for (int p = 0; p < 32; ++p) sb += (double)cpc[p * 64 + tid];
        red[tid] = sa * sb;
    }
    __syncthreads();
    if (tid == 0) {
        double s = 0.0;
        for (int k = 0; k < 64; ++k) s += red[k];
        sc[0] = s;
    } else if (tid == 1) {
        double s = 0.0;
        for (int k = 0; k < 64; ++k) s += Uupart[k];
        sc[2] = s;
    } else if (tid == 2) {
        double s = 0.0;
        for (int k = 64; k < 96; ++k) s += Uupart[k];
        sc[3] = s;
    }
    __syncthreads();
    {
        double gp = 0.0;
        for (int i = tid; i < 2048; i += 256) gp += (double)Gpart[i];
        red[tid] = gp;
    }
    __syncthreads();
    for (int s2 = 128; s2 > 0; s2 >>= 1) {
        if (tid < s2) red[tid] += red[tid + s2];
        __syncthreads();
    }
    if (tid == 0) sc[1] = red[0];
    __syncthreads();
    double S = sc[0];
    {
        int p = tid >> 2, q0 = (tid & 3) * 16;
        for (int q = q0; q < q0 + 16; ++q) {
            double s = 0.0;
            for (int k = 0; k < 64; ++k)
                s += (double)Aseg[p * 64 + k] * (double)Bseg[q * 64 + k];
            TrrG[p * 64 + q] = (float)(s / S);
        }
    }
    __syncthreads();
    if (tid < 64) {
        double s = 0.0;
        for (int q = 0; q < 64; ++q) s += (double)TrrG[tid * 64 + q];
        Prx[tid] = s;
    } else if (tid < 128) {
        int q = tid - 64;
        double s = 0.0;
        for (int pp = 0; pp < 64; ++pp) s += (double)TrrG[pp * 64 + q];
        Pry[q] = s;
    }
    __syncthreads();
    const double EPSd = 1e-15;
    double part = 0.0;
    for (int i = tid; i < 4096; i += 256) {
        double t = (double)TrrG[i];
        double txy = Prx[i >> 6] * Pry[i & 63];
        part += t * log((t + EPSd) / (txy + EPSd));
    }
    red[tid] = part;
    __syncthreads();
    for (int s2 = 128; s2 > 0; s2 >>= 1) {
        if (tid < s2) red[tid] += red[tid + s2];
        __syncthreads();
    }
    if (tid == 0) {
        const double inv_ln2 = 1.4426950408889634;
        double mi_red = red[0] * inv_ln2;
        double G = sc[1], Uu = sc[2], Vv = sc[3];
        double log2S = log(S) * inv_ln2;
        double mi_org = G / S + log2S - (Uu + Vv) / S;
        double loss = log(1.0 + fabs(1.0 - mi_red / mi_org));
        out[0] = (float)loss;
    }
}

extern "C" void kernel_launch(void* const* d_in, const int* in_sizes, int n_in,
                              void* d_out, int out_size, void* d_ws, size_t ws_size,
                              hipStream_t stream) {
    const float* Ur = (const float*)d_in[0];
    const float* Uc = (const float*)d_in[1];
    float* out = (float*)d_out;
    char* ws = (char*)d_ws;
    unsigned short* Ucb = (unsigned short*)(ws + OFF_UCB);
    float* segparts = (float*)(ws + OFF_SEGP);
    float* Gpart = (float*)(ws + OFF_GPART);
    float* cpr   = (float*)(ws + OFF_CPR);
    float* cpc   = (float*)(ws + OFF_CPC);
    double* Uupart = (double*)(ws + OFF_UUP);
    float* Aseg  = (float*)(ws + OFF_ASEG);
    float* Bseg  = (float*)(ws + OFF_BSEG);
    float* TrrG  = (float*)(ws + OFF_TRR);
    unsigned* tickets = (unsigned*)(ws + OFF_TK);

    k_prep<<<224, 256, 0, stream>>>(Ur, Uc, cpr, cpc, Ucb, tickets);
    k_main<<<NBLK_K2, 256, 0, stream>>>(Ur, Uc, (const unsigned char*)Ucb,
                                        Gpart, segparts, cpr, cpc, Uupart,
                                        Aseg, Bseg, TrrG, tickets, out);
}

// Round 10
// 251.894 us; speedup vs baseline: 1.4421x; 1.4421x over previous
//
#include <hip/hip_runtime.h>
#include <hip/hip_bf16.h>

#define N_INS 16384
#define N_ATT 8192
#define KDIM  64

typedef __attribute__((ext_vector_type(8))) short bf16x8;
typedef __attribute__((ext_vector_type(4))) float f32x4;

// ws layout (bytes) — buffers fully overwritten each launch (tickets zeroed by K1):
// 0:       bf16 Ucb[8192*64] (1 MiB, fragment-order tiles)
// 1048576: float segparts[96][4096] ([0,64)=Ur, [64,96)=Uc)
// 2621440: float Gpart[2048]
// 2629632: float cpr[64][64]
// 2646016: float cpc[32][64]
// 2654208: double Uupart[96]
// 2654976: float Aseg[4096]
// 2671360: float Bseg[4096]
// 2687744: unsigned tickets[2]
#define OFF_UCB    0
#define OFF_SEGP   1048576
#define OFF_GPART  2621440
#define OFF_CPR    2629632
#define OFF_CPC    2646016
#define OFF_UUP    2654208
#define OFF_ASEG   2654976
#define OFF_BSEG   2671360
#define OFF_TK     2687744

#define NBLK_HEAVY 2048
#define NBLK_PASS  96
#define NBLK_K2    (NBLK_HEAVY + NBLK_PASS)

__device__ __forceinline__ unsigned short f2bf(float x) {
    unsigned u = __float_as_uint(x);
    u = (u + 0x7FFFu + ((u >> 16) & 1u)) >> 16;   // RNE
    return (unsigned short)u;
}

__device__ __forceinline__ float wave_red(float v) {
#pragma unroll
    for (int o = 32; o > 0; o >>= 1) v += __shfl_down(v, o, 64);
    return v;
}

// ---- K1: convert Uc->bf16 fragment tiles, colsum partials, zero tickets ----
// blocks [0,128): convert. [128,192): Ur colsums (256 rows) -> cpr[64].
// [192,224): Uc colsums (256 rows) -> cpc[32].
__global__ void k_prep(const float* __restrict__ Ur, const float* __restrict__ Uc,
                       float* __restrict__ cpr, float* __restrict__ cpc,
                       unsigned short* __restrict__ Ucb, unsigned* __restrict__ tickets) {
    int blk = blockIdx.x, tid = threadIdx.x;
    if (blk < 128) {
        int gid = blk * 256 + tid;
        for (int c = gid; c < N_ATT * 8; c += 32768) {
            int r = c >> 3, q = c & 7;
            const float4* src = (const float4*)(Uc + (size_t)r * 64 + q * 8);
            float4 x0 = src[0], x1 = src[1];
            uint4 v;
            v.x = (unsigned)f2bf(x0.x) | ((unsigned)f2bf(x0.y) << 16);
            v.y = (unsigned)f2bf(x0.z) | ((unsigned)f2bf(x0.w) << 16);
            v.z = (unsigned)f2bf(x1.x) | ((unsigned)f2bf(x1.y) << 16);
            v.w = (unsigned)f2bf(x1.z) | ((unsigned)f2bf(x1.w) << 16);
            int m = r & 15, t = r >> 4;
            int woff = (q < 4) ? (q * 256 + m * 16) : (1024 + (q - 4) * 256 + m * 16);
            *(uint4*)((unsigned char*)Ucb + (size_t)t * 2048 + woff) = v;
        }
        return;
    }
    if (blk == 128 && tid == 0) { tickets[0] = 0u; tickets[1] = 0u; }
    __shared__ float cs2[256];
    bool isUr = blk < 192;
    int b = isUr ? (blk - 128) : (blk - 192);
    const float* base = (isUr ? Ur : Uc) + (size_t)b * 256 * KDIM;
    float* dst = (isUr ? cpr : cpc) + b * 64;
    int col = tid & 63, r0 = tid >> 6;
    float s = 0.f;
    for (int r = r0; r < 256; r += 4) s += base[r * KDIM + col];
    cs2[tid] = s;
    __syncthreads();
    if (tid < 64) dst[tid] = cs2[tid] + cs2[tid + 64] + cs2[tid + 128] + cs2[tid + 192];
}

// ---- K2: heavy (blocks<2048, NO fences/tickets) + pass (96, ticket fold) ----
// R9 lesson: 2144 per-block device fences (__threadfence on 8 non-coherent XCD
// L2s => L2 writeback each) cost ~300us. Heavy and pass are mutually independent
// (heavy needs Ucb, pass needs cpr/cpc — both from K1), so heavy blocks write
// Gpart with a plain store and EXIT. Only the 96 pass blocks run the ticket
// (fold segparts -> Aseg/Bseg); k_final consumes via kernel-boundary coherence.
__global__ __launch_bounds__(256)
void k_main(const float* __restrict__ Ur, const float* __restrict__ Uc,
            const unsigned char* __restrict__ Ucb,
            float* __restrict__ Gpart, float* __restrict__ segparts,
            const float* __restrict__ cpr, const float* __restrict__ cpc,
            double* __restrict__ Uupart,
            float* __restrict__ Aseg, float* __restrict__ Bseg,
            unsigned* __restrict__ tickets) {
    __shared__ __align__(16) unsigned char smem[17696];
    __shared__ int flag1;
    int tid = threadIdx.x, blk = blockIdx.x;
    int wvi = tid >> 6, lane = tid & 63;

    if (blk < NBLK_HEAVY) {
        // ---------- heavy: G += d*log2(d), bf16 MFMA, register-pipelined B ----------
        float* gsh = (float*)smem;
        int quad = lane >> 4, m = lane & 15;
        int rb = blk & 127, cc = blk >> 7;
        int row0 = rb * 128 + wvi * 32;
        bf16x8 a[2][2];
#pragma unroll
        for (int t = 0; t < 2; ++t) {
            int ridx = row0 + t * 16 + m;
            const float* rp = Ur + (size_t)ridx * 64 + quad * 8;
#pragma unroll
            for (int h = 0; h < 2; ++h) {
                const float* rph = rp + h * 32;
                float4 x0 = *(const float4*)rph;
                float4 x1 = *(const float4*)(rph + 4);
                bf16x8 f;
                f[0] = (short)f2bf(x0.x); f[1] = (short)f2bf(x0.y);
                f[2] = (short)f2bf(x0.z); f[3] = (short)f2bf(x0.w);
                f[4] = (short)f2bf(x1.x); f[5] = (short)f2bf(x1.y);
                f[6] = (short)f2bf(x1.z); f[7] = (short)f2bf(x1.w);
                a[t][h] = f;
            }
        }
        const unsigned char* gB = Ucb + (size_t)(cc * 32) * 2048 + lane * 16;
        bf16x8 c00 = *(const bf16x8*)(gB);
        bf16x8 c01 = *(const bf16x8*)(gB + 1024);
        bf16x8 c10 = *(const bf16x8*)(gB + 2048);
        bf16x8 c11 = *(const bf16x8*)(gB + 3072);
        float g = 0.f;
#pragma unroll 1
        for (int pt = 0; pt < 16; ++pt) {
            int npt = (pt < 15) ? (pt + 1) : 15;
            const unsigned char* nb = gB + (size_t)npt * 4096;
            bf16x8 n00 = *(const bf16x8*)(nb);
            bf16x8 n01 = *(const bf16x8*)(nb + 1024);
            bf16x8 n10 = *(const bf16x8*)(nb + 2048);
            bf16x8 n11 = *(const bf16x8*)(nb + 3072);
            f32x4 acc00 = {0.f,0.f,0.f,0.f}, acc01 = {0.f,0.f,0.f,0.f};
            f32x4 acc10 = {0.f,0.f,0.f,0.f}, acc11 = {0.f,0.f,0.f,0.f};
            acc00 = __builtin_amdgcn_mfma_f32_16x16x32_bf16(a[0][0], c00, acc00, 0, 0, 0);
            acc00 = __builtin_amdgcn_mfma_f32_16x16x32_bf16(a[0][1], c01, acc00, 0, 0, 0);
            acc10 = __builtin_amdgcn_mfma_f32_16x16x32_bf16(a[1][0], c00, acc10, 0, 0, 0);
            acc10 = __builtin_amdgcn_mfma_f32_16x16x32_bf16(a[1][1], c01, acc10, 0, 0, 0);
            acc01 = __builtin_amdgcn_mfma_f32_16x16x32_bf16(a[0][0], c10, acc01, 0, 0, 0);
            acc01 = __builtin_amdgcn_mfma_f32_16x16x32_bf16(a[0][1], c11, acc01, 0, 0, 0);
            acc11 = __builtin_amdgcn_mfma_f32_16x16x32_bf16(a[1][0], c10, acc11, 0, 0, 0);
            acc11 = __builtin_amdgcn_mfma_f32_16x16x32_bf16(a[1][1], c11, acc11, 0, 0, 0);
            // tile-sum is permutation-invariant -> C/D layout irrelevant;
            // dropping +eps*S (~2e-6 vs d~16) perturbs mi_org ~2e-7 << threshold
#pragma unroll
            for (int e = 0; e < 4; ++e) {
                float d0 = acc00[e]; g += d0 * __log2f(d0);
                float d1 = acc01[e]; g += d1 * __log2f(d1);
                float d2 = acc10[e]; g += d2 * __log2f(d2);
                float d3 = acc11[e]; g += d3 * __log2f(d3);
            }
            c00 = n00; c01 = n01; c10 = n10; c11 = n11;
        }
        float gw = wave_red(g);
        if (lane == 0) gsh[wvi] = gw;
        __syncthreads();
        if (tid == 0) Gpart[blk] = gsh[0] + gsh[1] + gsh[2] + gsh[3];
        return;                                    // no fence, no ticket
    }

    // ---------- pass: argmax + weighted sums (R8 structure, proven) ----------
    float* Part = (float*)smem;
    float* wv   = (float*)(smem + 16384);
    int*   bins = (int*)(smem + 16640);
    float* psum = (float*)(smem + 17664);
    bool isUr = blk < (NBLK_HEAVY + 64);
    int b = isUr ? (blk - NBLK_HEAVY) : (blk - NBLK_HEAVY - 64);
    const float* M = isUr ? Ur : Uc;
    const float* cpw = isUr ? cpc : cpr;
    int nbw = isUr ? 32 : 64;
    int segidx = isUr ? b : (64 + b);
    int base_row = b * 256;

    if (tid < 64) {
        float s = 0.f;
        for (int p = 0; p < nbw; ++p) s += cpw[p * 64 + tid];
        wv[tid] = s;
    }
    for (int i = tid; i < 4096; i += 256) Part[i] = 0.f;
    __syncthreads();

    {   // phase 1: row-per-thread argmax + dot (pure VALU)
        int row = base_row + tid;
        const float* rp = M + (size_t)row * KDIM;
        float best = -1e30f; int bidx = 0; float u = 0.f;
#pragma unroll
        for (int k = 0; k < 64; k += 4) {
            float4 v = *(const float4*)(rp + k);
            if (v.x > best) { best = v.x; bidx = k; }
            if (v.y > best) { best = v.y; bidx = k + 1; }
            if (v.z > best) { best = v.z; bidx = k + 2; }
            if (v.w > best) { best = v.w; bidx = k + 3; }
            u += v.x * wv[k] + v.y * wv[k + 1] + v.z * wv[k + 2] + v.w * wv[k + 3];
        }
        bins[tid] = bidx;
        float p = u * __log2f(u);
        float pw = wave_red(p);
        if (lane == 0) psum[wvi] = pw;
    }
    __syncthreads();
    {   // phase 2: one fire-and-forget ds_add per row per wave
        int r0 = wvi * 64;
        const float* Mb = M + (size_t)(base_row + r0) * 64 + lane;
#pragma unroll 4
        for (int r = 0; r < 64; ++r) {
            int bb = bins[r0 + r];
            float val = Mb[(size_t)r * 64];
            atomicAdd(&Part[bb * 64 + lane], val);
        }
    }
    __syncthreads();
    float* sp = segparts + (size_t)segidx * 4096;
    for (int i = tid; i < 4096; i += 256) sp[i] = Part[i];
    if (tid == 0)
        Uupart[segidx] = (double)psum[0] + (double)psum[1]
                       + (double)psum[2] + (double)psum[3];
    // ticket among the 96 pass blocks ONLY: last one folds segparts->Aseg/Bseg
    __threadfence();
    __syncthreads();
    if (tid == 0) { unsigned old = atomicAdd(&tickets[0], 1u); flag1 = (old == NBLK_PASS - 1); }
    __syncthreads();
    if (flag1) {
        __threadfence();                          // acquire published segparts
        for (int j = tid; j < 4096; j += 256) {
            float sa = 0.f, sb = 0.f;
            for (int p = 0; p < 64; ++p)  sa += segparts[(size_t)p * 4096 + j];
            for (int p = 64; p < 96; ++p) sb += segparts[(size_t)p * 4096 + j];
            Aseg[j] = sa; Bseg[j] = sb;
        }
    }
}

// ---- K3: S, G, Uu/Vv from partials; reduced-table MI; assemble loss ----
__global__ void k_final(const float* __restrict__ Aseg, const float* __restrict__ Bseg,
                        const float* __restrict__ cpr, const float* __restrict__ cpc,
                        const float* __restrict__ Gpart, const double* __restrict__ Uupart,
                        float* __restrict__ out) {
    __shared__ double Trr[4096];
    __shared__ double Prx[64], Pry[64];
    __shared__ double red[256];
    __shared__ double up[96];
    __shared__ double Ssh, Gsh, Uush, Vvsh;
    int tid = threadIdx.x;
    if (tid < 96) up[tid] = Uupart[tid];
    if (tid < 64) {
        double sa = 0.0, sb = 0.0;
        for (int p = 0; p < 64; ++p) sa += (double)cpr[p * 64 + tid];
        for (int p = 0; p < 32; ++p) sb += (double)cpc[p * 64 + tid];
        red[tid] = sa * sb;
    }
    __syncthreads();
    if (tid == 0) {
        double s = 0.0;
        for (int k = 0; k < 64; ++k) s += red[k];
        Ssh = s;
    } else if (tid == 1) {
        double s = 0.0;
        for (int k = 0; k < 64; ++k) s += up[k];
        Uush = s;
    } else if (tid == 2) {
        double s = 0.0;
        for (int k = 64; k < 96; ++k) s += up[k];
        Vvsh = s;
    }
    __syncthreads();
    {
        double gp = 0.0;
        for (int i = tid; i < 2048; i += 256) gp += (double)Gpart[i];
        red[tid] = gp;
    }
    __syncthreads();
    for (int s2 = 128; s2 > 0; s2 >>= 1) {
        if (tid < s2) red[tid] += red[tid + s2];
        __syncthreads();
    }
    if (tid == 0) Gsh = red[0];
    __syncthreads();
    double S = Ssh;
    int p = tid >> 2, qb = (tid & 3) * 16;
    for (int q = qb; q < qb + 16; ++q) {
        double s = 0.0;
        for (int k = 0; k < 64; ++k)
            s += (double)Aseg[p * 64 + k] * (double)Bseg[q * 64 + k];
        Trr[p * 64 + q] = s / S;
    }
    __syncthreads();
    if (tid < 64) {
        double s = 0.0;
        for (int q = 0; q < 64; ++q) s += Trr[tid * 64 + q];
        Prx[tid] = s;
    } else if (tid < 128) {
        int q = tid - 64;
        double s = 0.0;
        for (int pp = 0; pp < 64; ++pp) s += Trr[pp * 64 + q];
        Pry[q] = s;
    }
    __syncthreads();
    const double EPSd = 1e-15;
    double part = 0.0;
    for (int i = tid; i < 4096; i += 256) {
        double t = Trr[i];
        double txy = Prx[i >> 6] * Pry[i & 63];
        part += t * log((t + EPSd) / (txy + EPSd));
    }
    red[tid] = part;
    __syncthreads();
    for (int s2 = 128; s2 > 0; s2 >>= 1) {
        if (tid < s2) red[tid] += red[tid + s2];
        __syncthreads();
    }
    if (tid == 0) {
        const double inv_ln2 = 1.4426950408889634;
        double mi_red = red[0] * inv_ln2;
        double G = Gsh, Uu = Uush, Vv = Vvsh;
        double log2S = log(S) * inv_ln2;
        double mi_org = G / S + log2S - (Uu + Vv) / S;
        double loss = log(1.0 + fabs(1.0 - mi_red / mi_org));
        out[0] = (float)loss;
    }
}

extern "C" void kernel_launch(void* const* d_in, const int* in_sizes, int n_in,
                              void* d_out, int out_size, void* d_ws, size_t ws_size,
                              hipStream_t stream) {
    const float* Ur = (const float*)d_in[0];
    const float* Uc = (const float*)d_in[1];
    float* out = (float*)d_out;
    char* ws = (char*)d_ws;
    unsigned short* Ucb = (unsigned short*)(ws + OFF_UCB);
    float* segparts = (float*)(ws + OFF_SEGP);
    float* Gpart = (float*)(ws + OFF_GPART);
    float* cpr   = (float*)(ws + OFF_CPR);
    float* cpc   = (float*)(ws + OFF_CPC);
    double* Uupart = (double*)(ws + OFF_UUP);
    float* Aseg  = (float*)(ws + OFF_ASEG);
    float* Bseg  = (float*)(ws + OFF_BSEG);
    unsigned* tickets = (unsigned*)(ws + OFF_TK);

    k_prep<<<224, 256, 0, stream>>>(Ur, Uc, cpr, cpc, Ucb, tickets);
    k_main<<<NBLK_K2, 256, 0, stream>>>(Ur, Uc, (const unsigned char*)Ucb,
                                        Gpart, segparts, cpr, cpc, Uupart,
                                        Aseg, Bseg, tickets);
    k_final<<<1, 256, 0, stream>>>(Aseg, Bseg, cpr, cpc, Gpart, Uupart, out);
}

// Round 11
// 191.125 us; speedup vs baseline: 1.9006x; 1.3180x over previous
//
#include <hip/hip_runtime.h>
#include <hip/hip_bf16.h>

#define N_INS 16384
#define N_ATT 8192
#define KDIM  64

typedef __attribute__((ext_vector_type(8))) short bf16x8;
typedef __attribute__((ext_vector_type(4))) float f32x4;

// ws layout (bytes):
// 0:       bf16 Ucb[8192*64] (1 MiB, fragment-order tiles)   [K1 writes all]
// 1048576: float cpr[64][64]                                  [K1 writes all]
// 1064960: float cpc[32][64]                                  [K1 writes all]
// 1073152: float Aseg[4096]   (atomic-accumulated, K1 zeroes)
// 1089536: float Bseg[4096]   (atomic-accumulated, K1 zeroes)
// 1105920: double Gacc[96]    ([0,64)=G shards, [64,80)=Uu, [80,96)=Vv; K1 zeroes)
// 1106688: unsigned tickets[2] (K1 zeroes)
#define OFF_UCB    0
#define OFF_CPR    1048576
#define OFF_CPC    1064960
#define OFF_ASEG   1073152
#define OFF_BSEG   1089536
#define OFF_GACC   1105920
#define OFF_TK     1106688

#define NBLK_PASS  768            // blocks [0,768): pass (32 rows each)
#define NBLK_HEAVY 2048           // blocks [768, 2816): heavy
#define NBLK_K2    (NBLK_PASS + NBLK_HEAVY)

__device__ __forceinline__ unsigned short f2bf(float x) {
    unsigned u = __float_as_uint(x);
    u = (u + 0x7FFFu + ((u >> 16) & 1u)) >> 16;   // RNE
    return (unsigned short)u;
}

__device__ __forceinline__ float wave_red(float v) {
#pragma unroll
    for (int o = 32; o > 0; o >>= 1) v += __shfl_down(v, o, 64);
    return v;
}

// ---- K1: convert Uc->bf16 fragment tiles, colsum partials, zero accumulators ----
// blocks [0,128): convert. [128,192): Ur colsums (256 rows) -> cpr[64].
// [192,224): Uc colsums (256 rows) -> cpc[32]. block 224: zero Aseg/Bseg/Gacc/tickets.
__global__ void k_prep(const float* __restrict__ Ur, const float* __restrict__ Uc,
                       float* __restrict__ cpr, float* __restrict__ cpc,
                       unsigned short* __restrict__ Ucb,
                       float* __restrict__ Aseg, float* __restrict__ Bseg,
                       double* __restrict__ Gacc, unsigned* __restrict__ tickets) {
    int blk = blockIdx.x, tid = threadIdx.x;
    if (blk < 128) {
        int gid = blk * 256 + tid;
        for (int c = gid; c < N_ATT * 8; c += 32768) {
            int r = c >> 3, q = c & 7;
            const float4* src = (const float4*)(Uc + (size_t)r * 64 + q * 8);
            float4 x0 = src[0], x1 = src[1];
            uint4 v;
            v.x = (unsigned)f2bf(x0.x) | ((unsigned)f2bf(x0.y) << 16);
            v.y = (unsigned)f2bf(x0.z) | ((unsigned)f2bf(x0.w) << 16);
            v.z = (unsigned)f2bf(x1.x) | ((unsigned)f2bf(x1.y) << 16);
            v.w = (unsigned)f2bf(x1.z) | ((unsigned)f2bf(x1.w) << 16);
            int m = r & 15, t = r >> 4;
            int woff = (q < 4) ? (q * 256 + m * 16) : (1024 + (q - 4) * 256 + m * 16);
            *(uint4*)((unsigned char*)Ucb + (size_t)t * 2048 + woff) = v;
        }
        return;
    }
    if (blk == 224) {
        float4 z4 = {0.f, 0.f, 0.f, 0.f};
        for (int i = tid; i < 1024; i += 256) ((float4*)Aseg)[i] = z4;
        for (int i = tid; i < 1024; i += 256) ((float4*)Bseg)[i] = z4;
        if (tid < 96) Gacc[tid] = 0.0;
        if (tid == 0) { tickets[0] = 0u; tickets[1] = 0u; }
        return;
    }
    __shared__ float cs2[256];
    bool isUr = blk < 192;
    int b = isUr ? (blk - 128) : (blk - 192);
    const float* base = (isUr ? Ur : Uc) + (size_t)b * 256 * KDIM;
    float* dst = (isUr ? cpr : cpc) + b * 64;
    int col = tid & 63, r0 = tid >> 6;
    float s = 0.f;
    for (int r = r0; r < 256; r += 4) s += base[r * KDIM + col];
    cs2[tid] = s;
    __syncthreads();
    if (tid < 64) dst[tid] = cs2[tid] + cs2[tid + 64] + cs2[tid + 128] + cs2[tid + 192];
}

// ---- K2: pass (768 blocks, first) + heavy (2048) + ticketed final ----
// All cross-block data flows through DEVICE ATOMICS (coherent by definition,
// no __threadfence -> no per-block L2 writeback, R9's 300us disease).
// Ticket: atomics drained (s_waitcnt 0) + __syncthreads before the increment;
// the block observing count==NBLK-1 runs the final math. No spin-waits.
// Every path uses <= ~9KB LDS (R10 lesson: the fattest path's LDS allocation
// throttles heavy's blocks/CU).
__global__ __launch_bounds__(256)
void k_main(const float* __restrict__ Ur, const float* __restrict__ Uc,
            const unsigned char* __restrict__ Ucb,
            const float* __restrict__ cpr, const float* __restrict__ cpc,
            float* __restrict__ Aseg, float* __restrict__ Bseg,
            double* __restrict__ Gacc, unsigned* __restrict__ tickets,
            float* __restrict__ out) {
    __shared__ __align__(16) unsigned char smem[9216];
    __shared__ float gshW[4];
    __shared__ int flagS;
    int tid = threadIdx.x, blk = blockIdx.x;
    int wvi = tid >> 6, lane = tid & 63;

    if (blk < NBLK_PASS) {
        // ---------- pass: 32 rows, coalesced LDS stage, global-atomic segsum ----------
        float* stage = (float*)smem;                 // [32][65] stride-65, 8320 B
        int*   bins  = (int*)(smem + 8320);          // 32 ints
        float* wv    = (float*)(smem + 8448);        // 64 f32
        bool isUr = blk < 512;
        int b = isUr ? blk : (blk - 512);
        const float* M = isUr ? Ur : Uc;
        float* Seg = isUr ? Aseg : Bseg;
        int base_row = b * 32;

        if (tid < 64) {                              // weights = colsum of OTHER matrix
            const float* cpw = isUr ? cpc : cpr;
            int nbw = isUr ? 32 : 64;
            float s = 0.f;
            for (int p = 0; p < nbw; ++p) s += cpw[p * 64 + tid];
            wv[tid] = s;
        }
        // stage 32 rows (8 KB) coalesced; scalar ds_writes, stride 65 (bank-clean)
        const float* Mb = M + (size_t)base_row * 64;
        for (int i = tid; i < 2048; i += 256)
            stage[(i >> 6) * 65 + (i & 63)] = Mb[i];
        __syncthreads();

        if (tid < 32) {                              // argmax + dot, row per lane
            float* rp = stage + tid * 65;
            float best = -1e30f; int bidx = 0; float u = 0.f;
            for (int k = 0; k < 64; ++k) {
                float v = rp[k];                     // banks (tid+k)%32: conflict-free
                if (v > best) { best = v; bidx = k; }  // strict >: first-index tie-break
                u += v * wv[k];
            }
            bins[tid] = bidx;
            float p = (tid < 32) ? u * __log2f(u) : 0.f;
            // lanes 32-63 inactive; reduce within wave 0 below
            float pw = p;
#pragma unroll
            for (int o = 16; o > 0; o >>= 1) pw += __shfl_down(pw, o, 64);
            if (tid == 0) {
                double* acc = Gacc + (isUr ? (64 + (b & 15)) : (80 + (b & 15)));
                atomicAdd(acc, (double)pw);
            }
        }
        __syncthreads();
        // phase 2: wave w handles rows w*8..+8; one global atomic per row per lane
        {
            int r0 = wvi * 8;
            for (int r = r0; r < r0 + 8; ++r) {
                int bb = bins[r];                    // LDS broadcast: free
                float val = stage[r * 65 + lane];    // banks (r+lane)%32: free
                atomicAdd(&Seg[bb * 64 + lane], val);   // fire-and-forget
            }
        }
    } else {
        // ---------- heavy: G += d*log2(d), bf16 MFMA, register-pipelined B ----------
        int hb = blk - NBLK_PASS;
        int quad = lane >> 4, m = lane & 15;
        int rb = hb & 127, cc = hb >> 7;
        int row0 = rb * 128 + wvi * 32;
        bf16x8 a[2][2];
#pragma unroll
        for (int t = 0; t < 2; ++t) {
            int ridx = row0 + t * 16 + m;
            const float* rp = Ur + (size_t)ridx * 64 + quad * 8;
#pragma unroll
            for (int h = 0; h < 2; ++h) {
                const float* rph = rp + h * 32;
                float4 x0 = *(const float4*)rph;
                float4 x1 = *(const float4*)(rph + 4);
                bf16x8 f;
                f[0] = (short)f2bf(x0.x); f[1] = (short)f2bf(x0.y);
                f[2] = (short)f2bf(x0.z); f[3] = (short)f2bf(x0.w);
                f[4] = (short)f2bf(x1.x); f[5] = (short)f2bf(x1.y);
                f[6] = (short)f2bf(x1.z); f[7] = (short)f2bf(x1.w);
                a[t][h] = f;
            }
        }
        const unsigned char* gB = Ucb + (size_t)(cc * 32) * 2048 + lane * 16;
        bf16x8 c00 = *(const bf16x8*)(gB);
        bf16x8 c01 = *(const bf16x8*)(gB + 1024);
        bf16x8 c10 = *(const bf16x8*)(gB + 2048);
        bf16x8 c11 = *(const bf16x8*)(gB + 3072);
        float g = 0.f;
#pragma unroll 1
        for (int pt = 0; pt < 16; ++pt) {
            int npt = (pt < 15) ? (pt + 1) : 15;
            const unsigned char* nb = gB + (size_t)npt * 4096;
            bf16x8 n00 = *(const bf16x8*)(nb);
            bf16x8 n01 = *(const bf16x8*)(nb + 1024);
            bf16x8 n10 = *(const bf16x8*)(nb + 2048);
            bf16x8 n11 = *(const bf16x8*)(nb + 3072);
            f32x4 acc00 = {0.f,0.f,0.f,0.f}, acc01 = {0.f,0.f,0.f,0.f};
            f32x4 acc10 = {0.f,0.f,0.f,0.f}, acc11 = {0.f,0.f,0.f,0.f};
            acc00 = __builtin_amdgcn_mfma_f32_16x16x32_bf16(a[0][0], c00, acc00, 0, 0, 0);
            acc00 = __builtin_amdgcn_mfma_f32_16x16x32_bf16(a[0][1], c01, acc00, 0, 0, 0);
            acc10 = __builtin_amdgcn_mfma_f32_16x16x32_bf16(a[1][0], c00, acc10, 0, 0, 0);
            acc10 = __builtin_amdgcn_mfma_f32_16x16x32_bf16(a[1][1], c01, acc10, 0, 0, 0);
            acc01 = __builtin_amdgcn_mfma_f32_16x16x32_bf16(a[0][0], c10, acc01, 0, 0, 0);
            acc01 = __builtin_amdgcn_mfma_f32_16x16x32_bf16(a[0][1], c11, acc01, 0, 0, 0);
            acc11 = __builtin_amdgcn_mfma_f32_16x16x32_bf16(a[1][0], c10, acc11, 0, 0, 0);
            acc11 = __builtin_amdgcn_mfma_f32_16x16x32_bf16(a[1][1], c11, acc11, 0, 0, 0);
            // tile-sum is permutation-invariant -> C/D layout irrelevant;
            // dropping +eps*S (~2e-6 vs d~16) perturbs mi_org ~2e-7 << threshold
#pragma unroll
            for (int e = 0; e < 4; ++e) {
                float d0 = acc00[e]; g += d0 * __log2f(d0);
                float d1 = acc01[e]; g += d1 * __log2f(d1);
                float d2 = acc10[e]; g += d2 * __log2f(d2);
                float d3 = acc11[e]; g += d3 * __log2f(d3);
            }
            c00 = n00; c01 = n01; c10 = n10; c11 = n11;
        }
        float gw = wave_red(g);
        if (lane == 0) gshW[wvi] = gw;
        __syncthreads();
        if (tid == 0) {
            float gs = gshW[0] + gshW[1] + gshW[2] + gshW[3];
            atomicAdd(&Gacc[hb & 63], (double)gs);   // 32 blocks/shard: cheap
        }
    }

    // ---------- common tail: drain atomics, take ticket, maybe run final ----------
    __builtin_amdgcn_s_waitcnt(0);                   // all this thread's vmem acked
    __syncthreads();                                 // whole block drained
    if (tid == 0) { unsigned old = atomicAdd(&tickets[0], 1u); flagS = (old == NBLK_K2 - 1); }
    __syncthreads();
    if (!flagS) return;

    // final: everything we read was atomic-written (memory-side, coherent) or
    // K1-produced (kernel-boundary coherent). Cold local L2 -> no staleness.
    float*  Prx = (float*)smem;                      // 64 f32
    float*  Pry = (float*)(smem + 256);              // 64 f32
    double* sc  = (double*)(smem + 512);             // S,G,Uu,Vv
    double* red = (double*)(smem + 1024);            // 256 f64
    if (tid < 64) {
        double sa = 0.0, sb = 0.0;
        for (int p = 0; p < 64; ++p) sa += (double)cpr[p * 64 + tid];
        for (int p = 0; p < 32; ++p) sb += (double)cpc[p * 64 + tid];
        red[tid] = sa * sb;
        Prx[tid] = 0.f; Pry[tid] = 0.f;
    }
    __syncthreads();
    if (tid == 0) {
        double s = 0.0;
        for (int k = 0; k < 64; ++k) s += red[k];
        sc[0] = s;
        double gg = 0.0;
        for (int k = 0; k < 64; ++k) gg += Gacc[k];
        sc[1] = gg;
    } else if (tid == 1) {
        double s = 0.0;
        for (int k = 64; k < 80; ++k) s += Gacc[k];
        sc[2] = s;
    } else if (tid == 2) {
        double s = 0.0;
        for (int k = 80; k < 96; ++k) s += Gacc[k];
        sc[3] = s;
    }
    __syncthreads();
    double S = sc[0];
    // Trr tile: thread owns row p = tid>>2, cols q0..q0+15; keep t in registers
    int p = tid >> 2, q0 = (tid & 3) * 16;
    float tloc[16];
    {
        float prow_sum = 0.f;
        for (int qi = 0; qi < 16; ++qi) {
            int q = q0 + qi;
            double s = 0.0;
            for (int k = 0; k < 64; ++k)
                s += (double)Aseg[p * 64 + k] * (double)Bseg[q * 64 + k];
            float t = (float)(s / S);
            tloc[qi] = t;
            prow_sum += t;
            atomicAdd(&Pry[q], t);
        }
        atomicAdd(&Prx[p], prow_sum);
    }
    __syncthreads();
    {
        const double EPSd = 1e-15;
        double part = 0.0;
        for (int qi = 0; qi < 16; ++qi) {
            double t = (double)tloc[qi];
            double txy = (double)Prx[p] * (double)Pry[q0 + qi];
            part += t * log((t + EPSd) / (txy + EPSd));
        }
        red[tid] = part;
    }
    __syncthreads();
    for (int s2 = 128; s2 > 0; s2 >>= 1) {
        if (tid < s2) red[tid] += red[tid + s2];
        __syncthreads();
    }
    if (tid == 0) {
        const double inv_ln2 = 1.4426950408889634;
        double mi_red = red[0] * inv_ln2;
        double G = sc[1], Uu = sc[2], Vv = sc[3];
        double log2S = log(S) * inv_ln2;
        double mi_org = G / S + log2S - (Uu + Vv) / S;
        double loss = log(1.0 + fabs(1.0 - mi_red / mi_org));
        out[0] = (float)loss;
    }
}

extern "C" void kernel_launch(void* const* d_in, const int* in_sizes, int n_in,
                              void* d_out, int out_size, void* d_ws, size_t ws_size,
                              hipStream_t stream) {
    const float* Ur = (const float*)d_in[0];
    const float* Uc = (const float*)d_in[1];
    float* out = (float*)d_out;
    char* ws = (char*)d_ws;
    unsigned short* Ucb = (unsigned short*)(ws + OFF_UCB);
    float* cpr   = (float*)(ws + OFF_CPR);
    float* cpc   = (float*)(ws + OFF_CPC);
    float* Aseg  = (float*)(ws + OFF_ASEG);
    float* Bseg  = (float*)(ws + OFF_BSEG);
    double* Gacc = (double*)(ws + OFF_GACC);
    unsigned* tickets = (unsigned*)(ws + OFF_TK);

    k_prep<<<225, 256, 0, stream>>>(Ur, Uc, cpr, cpc, Ucb, Aseg, Bseg, Gacc, tickets);
    k_main<<<NBLK_K2, 256, 0, stream>>>(Ur, Uc, (const unsigned char*)Ucb,
                                        cpr, cpc, Aseg, Bseg, Gacc, tickets, out);
}